// Round 8
// baseline (64.997 us; speedup 1.0000x reference)
//
#include <hip/hip_runtime.h>

#define TT 32     // tags
#define LL 16     // max span length
#define PD 4      // prefetch depth (steps); 16 loads/step*4 = 64 outstanding ~ vmcnt cap
#define BURN 32   // burn-in steps for chunk-parallel scan
#define KCH 16    // chunk payload length (steps)

// lane<->lane^32 sum via permlane32_swap (VALU) with shfl fallback
__device__ __forceinline__ float swap_sum(float x) {
#if __has_builtin(__builtin_amdgcn_permlane32_swap)
    typedef unsigned int u2 __attribute__((ext_vector_type(2)));
    u2 r = __builtin_amdgcn_permlane32_swap(__float_as_uint(x), __float_as_uint(x),
                                            false, false);
    return __uint_as_float(r.x) + __uint_as_float(r.y);
#else
    return x + __shfl_xor(x, 32);
#endif
}

// ---------------------------------------------------------------------------
// Chunk-parallel scan, DIRECT feats reads.
// Chunk c covers global steps [cK, (c+1)K). gstart = max(0, cK-BURN); chunks
// with gstart>0 start from an all-ones state and burn in (projective
// contraction forgets the init; absmax ~0 measured at BURN=64, est. per-seam
// error at BURN=32 is orders below the 2600 threshold). gstart==0 chunks use
// the exact boundary init. Each chunk reports m_end - m_pre of
// m(x)=log(sum_t H[t]) (m_pre at step cK-1, captured at block preb);
// chunk 0 reports absolute m_end; last chunk adds the terminal correction.
// Telescoped sum of ws2[0..C] = final LSE.
// ---------------------------------------------------------------------------
__launch_bounds__(64, 1)
__global__ void semicrf_chunk_kernel(const float* __restrict__ feats,
                                     const float* __restrict__ trans,
                                     const float* __restrict__ tbound,
                                     const float* __restrict__ w1p,
                                     const float* __restrict__ w2p,
                                     float* __restrict__ ws2,
                                     int S, int K, int C) {
    __shared__ float ldsS[TT];
    const int c = (int)blockIdx.x;
    const int lane = (int)threadIdx.x;
    const int t = lane & 31;
    const int h = lane >> 5;
    const float w1 = w1p[0];
    const float w2 = w2p[0];
    const int Sm1 = S - 1;

    int gstart = c * K - BURN;
    if (gstart < 0) gstart = 0;
    const bool exact0 = (gstart == 0);
    const int nb = ((c + 1) * K - gstart) >> 4;   // 16-step blocks in this chunk
    const int preb = (c * K - gstart) >> 4;       // block at whose head m_pre is taken

    const float* fp = feats + t;            // per-lane base (t component)
    unsigned loff[16];
#pragma unroll
    for (int l = 0; l < 16; ++l)
        loff[l] = (unsigned)l * (unsigned)Sm1 * 32u;   // plane-l base offset

    float trx[16];
#pragma unroll
    for (int i = 0; i < 16; ++i)
        trx[i] = __expf(w1 * trans[t * TT + h * 16 + i]);
    float trxsum = 0.0f;
#pragma unroll
    for (int i = 0; i < 16; ++i) trxsum += trx[i];

    float D[16];
#pragma unroll
    for (int k = 0; k < 16; ++k) D[k] = exact0 ? 0.0f : trxsum;
    if (!exact0) ldsS[t] = 1.0f;            // ones init (H_{-1} = 1)

    // prefetch ring of RAW feats values: rvr[st&3][l]
    float rvr[PD][16];
#pragma unroll
    for (int st = 0; st < PD; ++st) {
        const unsigned sb = (unsigned)(gstart + st) * 32u;
#pragma unroll
        for (int l = 0; l < 16; ++l)
            rvr[st][l] = fp[loff[l] + sb];
    }

    float etb0 = __expf(w1 * tbound[t]);
    float bem[16];
#pragma unroll
    for (int j = 0; j < 16; ++j) bem[j] = 0.0f;
    if (exact0) {
#pragma unroll
        for (int j = 0; j < 16; ++j)        // bemit[j] = feats[j][0][t]
            bem[j] = __expf(w2 * feats[(size_t)j * (size_t)S * 32u + (size_t)t]);
    }

    float mref = 0.0f, Svk = 1.0f, inv = 1.0f;
    int s0 = gstart;

#define SCRF_STEP(J, IS_B0, IS_FIRST, SCALED)                                 \
    {                                                                         \
        const int j_ = (J);                                                   \
        const int jn_ = (j_ - 1) & 15;                                        \
        /* this step's 16 emissions (exp at consume; off-chain). read ring */ \
        /* slot BEFORE the prefetch below overwrites it (PD==ring size). */   \
        float ew_[16];                                                        \
        _Pragma("unroll")                                                     \
        for (int l = 0; l < 16; ++l) ew_[l] = __expf(w2 * rvr[j_ & 3][l]);    \
        /* prefetch target s0+j_+PD into slot (j_+PD)&3 (== j_&3) */          \
        {                                                                     \
            int stq_ = s0 + j_ + PD;                                          \
            if (stq_ > Sm1) stq_ = Sm1;                                       \
            const unsigned sb_ = (unsigned)stq_ * 32u;                        \
            _Pragma("unroll")                                                 \
            for (int l = 0; l < 16; ++l)                                      \
                rvr[(j_ + PD) & 3][l] = fp[loff[l] + sb_];                    \
        }                                                                     \
        /* MVM from LDS (Sv written last step) -> D[jn_]  (chain head) */     \
        float Dn_;                                                            \
        if (IS_FIRST) {                                                       \
            Dn_ = 0.0f;                                                       \
        } else {                                                              \
            const float4* lp_ = (const float4*)ldsS;                          \
            float4 a0_ = lp_[h * 4 + 0];                                      \
            float4 a1_ = lp_[h * 4 + 1];                                      \
            float4 a2_ = lp_[h * 4 + 2];                                      \
            float4 a3_ = lp_[h * 4 + 3];                                      \
            float d0_ = fmaf(trx[0], a0_.x, fmaf(trx[1], a0_.y,               \
                        fmaf(trx[2], a0_.z, trx[3] * a0_.w)));                \
            float d1_ = fmaf(trx[4], a1_.x, fmaf(trx[5], a1_.y,               \
                        fmaf(trx[6], a1_.z, trx[7] * a1_.w)));                \
            float d2_ = fmaf(trx[8], a2_.x, fmaf(trx[9], a2_.y,               \
                        fmaf(trx[10], a2_.z, trx[11] * a2_.w)));              \
            float d3_ = fmaf(trx[12], a3_.x, fmaf(trx[13], a3_.y,             \
                        fmaf(trx[14], a3_.z, trx[15] * a3_.w)));              \
            float dh_ = (d0_ + d1_) + (d2_ + d3_);                            \
            Dn_ = SCALED ? dh_ * inv : dh_;                                   \
            D[jn_] = Dn_;                                                     \
        }                                                                     \
        /* partial over l=1..15 (independent of Dn_, schedules in the gap) */ \
        float q0_ = 0.f, q1_ = 0.f, q2_ = 0.f, q3_ = 0.f;                     \
        _Pragma("unroll")                                                     \
        for (int l = 1; l <= 9; l += 4) {                                     \
            q0_ = fmaf(D[(j_ - 1 - l) & 15], ew_[l + 0], q0_);                \
            q1_ = fmaf(D[(j_ - 2 - l) & 15], ew_[l + 1], q1_);                \
            q2_ = fmaf(D[(j_ - 3 - l) & 15], ew_[l + 2], q2_);                \
            q3_ = fmaf(D[(j_ - 4 - l) & 15], ew_[l + 3], q3_);                \
        }                                                                     \
        q0_ = fmaf(D[(j_ - 14) & 15], ew_[13], q0_);                          \
        q1_ = fmaf(D[(j_ - 15) & 15], ew_[14], q1_);                          \
        q2_ = fmaf(D[(j_ - 16) & 15], ew_[15], q2_);                          \
        float p15_ = (q0_ + q1_) + (q2_ + q3_);                               \
        p15_ = (t == 0) ? 0.0f : p15_;     /* O-tag: span len 1 only */       \
        float part_ = fmaf(Dn_, ew_[0], p15_);                                \
        float Sv_ = swap_sum(part_);                                          \
        if (IS_B0) {                                                          \
            float bt_ = etb0 * bem[j_];                                       \
            if (j_ > 0) bt_ = (t == 0) ? 0.0f : bt_;                          \
            Sv_ += bt_;                                                       \
        }                                                                     \
        ldsS[t] = Sv_;                                                        \
        Svk = Sv_;                                                            \
    }

    // ---- first 16-step block ----
    if (exact0) {
        SCRF_STEP(0, true, true, false)
#pragma unroll
        for (int j = 1; j < 16; ++j) {
            SCRF_STEP(j, true, false, false)
        }
    } else {
#pragma unroll
        for (int j = 0; j < 16; ++j) {
            SCRF_STEP(j, false, false, false)
        }
    }

    // ---- remaining blocks ----
    float m_pre = 0.0f;
    for (int b = 1; b < nb; ++b) {
        s0 += 16;
        if (b == preb) {   // capture m at global step c*K-1 (pre-rescale)
            float sv = Svk;
#pragma unroll
            for (int m = 1; m <= 16; m <<= 1) sv += __shfl_xor(sv, m);
            m_pre = mref + __logf(sv);
        }
        // re-anchor: divide all rows by max_t(Sv_last), recenter to e^-20
        float mx = Svk;
#pragma unroll
        for (int m = 1; m <= 16; m <<= 1)
            mx = fmaxf(mx, __shfl_xor(mx, m));
        inv = 2.0611536e-09f / mx;          // e^-20 / mx
        mref += __logf(mx) + 20.0f;
#pragma unroll
        for (int k = 0; k < 16; ++k) D[k] *= inv;

        SCRF_STEP(0, false, false, true)    // pending ldsS value gets *inv
#pragma unroll
        for (int j = 1; j < 16; ++j) {
            SCRF_STEP(j, false, false, false)
        }
    }
#undef SCRF_STEP

    // ---- chunk outputs ----
    float se = Svk;
#pragma unroll
    for (int m = 1; m <= 16; m <<= 1) se += __shfl_xor(se, m);
    float m_end = mref + __logf(se);
    float contrib = (preb == 0) ? m_end : (m_end - m_pre);
    if (lane == 0) ws2[c] = contrib;
    if (c == C - 1) {
        float etb1 = __expf(w1 * tbound[TT + t]);
        float sc = Svk * etb1;
#pragma unroll
        for (int m = 1; m <= 16; m <<= 1) sc += __shfl_xor(sc, m);
        if (lane == 0) ws2[C] = __logf(sc) - __logf(se);
    }
}

// ---------------------------------------------------------------------------
// Ordered reduction of the C+1 chunk contributions.
// ---------------------------------------------------------------------------
__global__ void stitch_kernel(const float* __restrict__ ws2,
                              float* __restrict__ out, int n) {
    const int lane = (int)threadIdx.x;
    float v = 0.0f;
    for (int i = lane; i < n; i += 64) v += ws2[i];
#pragma unroll
    for (int m = 1; m <= 32; m <<= 1) v += __shfl_xor(v, m);
    if (lane == 0) out[0] = v;
}

// ---------------------------------------------------------------------------
// Fallback (odd S / tiny ws): proven round-2 kernel, reads feats directly.
// ---------------------------------------------------------------------------
__launch_bounds__(64, 1)
__global__ void semicrf_scan_fb_kernel(const float* __restrict__ src,
                                       const float* __restrict__ trans,
                                       const float* __restrict__ tbound,
                                       const float* __restrict__ w1p,
                                       const float* __restrict__ w2p,
                                       float* __restrict__ out, int S) {
    __shared__ float4 ldsS4[8];
    const int lane = threadIdx.x;
    const int t = lane & 31;
    const int h = lane >> 5;
    const float w1 = w1p[0];
    const float w2 = w2p[0];
    const unsigned toff = (unsigned)t * 4u;
    const unsigned planeB = (unsigned)S * 128u;
    const size_t planeE = (size_t)S * TT;

    float trx[16];
#pragma unroll
    for (int i = 0; i < 16; ++i)
        trx[i] = __expf(w1 * trans[t * TT + h * 16 + i]);

    float D[16];
#pragma unroll
    for (int k = 0; k < 16; ++k) D[k] = 0.0f;

    unsigned off[16];
#pragma unroll
    for (int k = 0; k < 16; ++k) {
        int l = (-1 - k) & 15;
        int c = 0 - l; if (c < 0) c = 0;
        off[k] = (unsigned)(l * S + c) * 128u + toff;
    }

    float ring[4][16];
#pragma unroll
    for (int st = 0; st < 4; ++st) {
#pragma unroll
        for (int k = 0; k < 16; ++k)
            ring[st][k] = *(const float*)((const char*)src + off[k]);
        const int qr = st & 15;
        unsigned c = (unsigned)((st + 1 <= S - 1) ? st + 1 : S - 1);
#pragma unroll
        for (int k = 0; k < 16; ++k)
            off[k] = (k == qr) ? (c * 128u + toff) : (off[k] + planeB);
    }

    float etb0 = __expf(w1 * tbound[t]);
    float bem[16];
#pragma unroll
    for (int j = 0; j < 16; ++j)
        bem[j] = __expf(w2 * src[(size_t)j * planeE + (size_t)t]);

    float mref = 0.0f;
    float Svk = 1.0f;

#define FB_STEP(J, S0V, IS_B0)                                                \
    {                                                                         \
        const int j_ = (J);                                                   \
        float ewv[16];                                                        \
        _Pragma("unroll")                                                     \
        for (int k = 0; k < 16; ++k)                                          \
            ewv[k] = __expf(w2 * ring[j_ & 3][k]);                            \
        float p0 = 0.f, p1 = 0.f, p2 = 0.f, p3 = 0.f;                         \
        _Pragma("unroll")                                                     \
        for (int k = 0; k < 16; k += 4) {                                     \
            p0 = fmaf(D[k + 0], ewv[k + 0], p0);                              \
            p1 = fmaf(D[k + 1], ewv[k + 1], p1);                              \
            p2 = fmaf(D[k + 2], ewv[k + 2], p2);                              \
            p3 = fmaf(D[k + 3], ewv[k + 3], p3);                              \
        }                                                                     \
        float part = (p0 + p1) + (p2 + p3);                                   \
        {                                                                     \
            const int kp = (j_ - 1) & 15;                                     \
            float alt = D[kp] * ewv[kp];                                      \
            part = (t == 0) ? alt : part;                                     \
        }                                                                     \
        _Pragma("unroll")                                                     \
        for (int k = 0; k < 16; ++k)                                          \
            ring[(j_ + 4) & 3][k] =                                           \
                *(const float*)((const char*)src + off[k]);                   \
        {                                                                     \
            const int qr = (j_ + 4) & 15;                                     \
            long T1 = (long)(S0V) + j_ + 4 + 1;                               \
            unsigned c_ = (unsigned)(T1 <= (long)(S - 1) ? T1 : (long)(S - 1)); \
            _Pragma("unroll")                                                 \
            for (int k = 0; k < 16; ++k)                                      \
                off[k] = (k == qr) ? (c_ * 128u + toff) : (off[k] + planeB);  \
        }                                                                     \
        float Sv = part + __shfl_xor(part, 32);                               \
        if (IS_B0) {                                                          \
            float bt = etb0 * bem[j_];                                        \
            if (j_ > 0) bt = (t == 0) ? 0.0f : bt;                            \
            Sv += bt;                                                         \
        }                                                                     \
        ((float*)ldsS4)[t] = Sv;                                              \
        __syncthreads();                                                      \
        float4 a0 = ldsS4[h * 4 + 0];                                         \
        float4 a1 = ldsS4[h * 4 + 1];                                         \
        float4 a2 = ldsS4[h * 4 + 2];                                         \
        float4 a3 = ldsS4[h * 4 + 3];                                         \
        float dn0 = fmaf(trx[0],  a0.x, fmaf(trx[1],  a0.y,                   \
                    fmaf(trx[2],  a0.z, trx[3]  * a0.w)));                    \
        float dn1 = fmaf(trx[4],  a1.x, fmaf(trx[5],  a1.y,                   \
                    fmaf(trx[6],  a1.z, trx[7]  * a1.w)));                    \
        float dn2 = fmaf(trx[8],  a2.x, fmaf(trx[9],  a2.y,                   \
                    fmaf(trx[10], a2.z, trx[11] * a2.w)));                    \
        float dn3 = fmaf(trx[12], a3.x, fmaf(trx[13], a3.y,                   \
                    fmaf(trx[14], a3.z, trx[15] * a3.w)));                    \
        D[j_] = (dn0 + dn1) + (dn2 + dn3);                                    \
        Svk = Sv;                                                             \
    }

#pragma unroll
    for (int j = 0; j < 16; ++j) {
        FB_STEP(j, 0L, true)
    }
    const int nblocks = S / 16;
    long s0 = 16;
    for (int b = 1; b < nblocks; ++b) {
        float mx = Svk;
#pragma unroll
        for (int m = 1; m <= 16; m <<= 1)
            mx = fmaxf(mx, __shfl_xor(mx, m));
        float invv = 2.0611536e-09f / mx;
        mref += __logf(mx) + 20.0f;
#pragma unroll
        for (int k = 0; k < 16; ++k) D[k] *= invv;
#pragma unroll
        for (int j = 0; j < 16; ++j) {
            FB_STEP(j, s0, false)
        }
        s0 += 16;
    }
#undef FB_STEP

    float etb1 = __expf(w1 * tbound[TT + t]);
    float val = Svk * etb1;
#pragma unroll
    for (int m = 1; m <= 16; m <<= 1) val += __shfl_xor(val, m);
    if (lane == 0) out[0] = mref + __logf(val);
}

// ---------------------------------------------------------------------------
extern "C" void kernel_launch(void* const* d_in, const int* in_sizes, int n_in,
                              void* d_out, int out_size, void* d_ws, size_t ws_size,
                              hipStream_t stream) {
    const float* feats = (const float*)d_in[0];   // [L=16, S, T=32]
    const float* trans = (const float*)d_in[1];   // [T, T]
    const float* tb    = (const float*)d_in[2];   // [2, T]
    const float* w1    = (const float*)d_in[3];
    const float* w2    = (const float*)d_in[4];
    float* out = (float*)d_out;

    const int n = in_sizes[0];            // L*S*T
    const int S = n / (LL * TT);

    // K=16 chunks; every chunk's window is a multiple of 16 steps.
    int C = 0;
    if ((S & 15) == 0 && S >= 64) C = S >> 4;

    const size_t need = (size_t)(C + 2) * sizeof(float);
    if (C > 1 && ws_size >= need) {
        float* ws2 = (float*)d_ws;
        semicrf_chunk_kernel<<<C, 64, 0, stream>>>(feats, trans, tb, w1, w2,
                                                   ws2, S, KCH, C);
        stitch_kernel<<<1, 64, 0, stream>>>(ws2, out, C + 1);
    } else {
        semicrf_scan_fb_kernel<<<1, 64, 0, stream>>>(feats, trans, tb, w1, w2, out, S);
    }
}

// Round 9
// 55.971 us; speedup vs baseline: 1.1613x; 1.1613x over previous
//
#include <hip/hip_runtime.h>

#define TT 32     // tags
#define LL 16     // max span length
#define BURN 32   // burn-in steps for chunk-parallel scan
#define KCH 16    // chunk payload length (steps)

typedef __attribute__((address_space(3))) void lds_v;
typedef const __attribute__((address_space(1))) void glb_v;

// lane<->lane^32 sum via permlane32_swap (VALU) with shfl fallback
__device__ __forceinline__ float swap_sum(float x) {
#if __has_builtin(__builtin_amdgcn_permlane32_swap)
    typedef unsigned int u2 __attribute__((ext_vector_type(2)));
    u2 r = __builtin_amdgcn_permlane32_swap(__float_as_uint(x), __float_as_uint(x),
                                            false, false);
    return __uint_as_float(r.x) + __uint_as_float(r.y);
#else
    return x + __shfl_xor(x, 32);
#endif
}

// ---------------------------------------------------------------------------
// Chunk-parallel scan with LDS-staged group loads.
// Chunk c covers global steps [cK, (c+1)K); gstart = max(0, cK-BURN); chunks
// with gstart>0 burn in from an all-ones state (projective contraction,
// absmax ~0 verified at BURN=32). Per 8-step group: 16x global_load_lds
// (1KB contiguous per l-plane) -> LDS ring -> 8 steps of compute from LDS.
// Each chunk reports m_end - m_pre of m(x)=log(sum_t H[t]); chunk 0 reports
// absolute m_end; last chunk adds the terminal correction. ws2 telescopes.
// ---------------------------------------------------------------------------
__launch_bounds__(64, 1)
__global__ void semicrf_chunk_kernel(const float* __restrict__ feats,
                                     const float* __restrict__ trans,
                                     const float* __restrict__ tbound,
                                     const float* __restrict__ w1p,
                                     const float* __restrict__ w2p,
                                     float* __restrict__ ws2,
                                     int S, int K, int C, int swz) {
    __shared__ __align__(16) float ring[16 * 256];   // 16 planes x 8 steps x 32 t
    __shared__ float ldsS[TT];
    int c = (int)blockIdx.x;
    if (swz) c = (c & 7) * (C >> 3) + (c >> 3);      // XCD-contiguous chunks
    const int lane = (int)threadIdx.x;
    const int t = lane & 31;
    const int h = lane >> 5;
    const float w1 = w1p[0];
    const float w2 = w2p[0];
    const int Sm1 = S - 1;
    const int lane4 = lane * 4;

    int gstart = c * K - BURN;
    if (gstart < 0) gstart = 0;
    const bool exact0 = (gstart == 0);
    const int nb = ((c + 1) * K - gstart) >> 4;   // 16-step blocks in this chunk
    const int preb = (c * K - gstart) >> 4;       // block whose head captures m_pre

    float trx[16];
#pragma unroll
    for (int i = 0; i < 16; ++i)
        trx[i] = __expf(w1 * trans[t * TT + h * 16 + i]);
    float trxsum = 0.0f;
#pragma unroll
    for (int i = 0; i < 16; ++i) trxsum += trx[i];

    float D[16];
#pragma unroll
    for (int k = 0; k < 16; ++k) D[k] = exact0 ? 0.0f : trxsum;
    if (!exact0) ldsS[t] = 1.0f;            // ones init (H_{-1} = 1)

    float etb0 = __expf(w1 * tbound[t]);
    float bem[16];
#pragma unroll
    for (int j = 0; j < 16; ++j) bem[j] = 0.0f;
    if (exact0) {
#pragma unroll
        for (int j = 0; j < 16; ++j)        // bemit[j] = feats[j][0][t]
            bem[j] = __expf(w2 * feats[(size_t)j * (size_t)S * 32u + (size_t)t]);
    }

    float mref = 0.0f, Svk = 1.0f, inv = 1.0f;
    int s0 = gstart;

// stage 8 steps (GS..GS+7) of all 16 planes: 16x 1KB global->LDS
#define STAGE8(GS)                                                            \
    {                                                                         \
        const int gs_ = (GS);                                                 \
        _Pragma("unroll")                                                     \
        for (int l = 0; l < 16; ++l)                                          \
            __builtin_amdgcn_global_load_lds(                                 \
                (glb_v*)(feats + ((size_t)l * (size_t)Sm1 + (size_t)gs_) * 32 \
                         + lane4),                                            \
                (lds_v*)&ring[l * 256], 16, 0, 0);                            \
    }

#define SCRF_STEP(J, IS_B0, IS_FIRST, SCALED)                                 \
    {                                                                         \
        const int j_ = (J);                                                   \
        const int jn_ = (j_ - 1) & 15;                                        \
        /* 16 emissions from the LDS ring (conflict-free, bank = t) */        \
        float ew_[16];                                                        \
        _Pragma("unroll")                                                     \
        for (int l = 0; l < 16; ++l)                                          \
            ew_[l] = __expf(w2 * ring[l * 256 + (j_ & 7) * 32 + t]);          \
        /* MVM from LDS (Sv written last step) -> D[jn_]  (chain head) */     \
        float Dn_;                                                            \
        if (IS_FIRST) {                                                       \
            Dn_ = 0.0f;                                                       \
        } else {                                                              \
            const float4* lp_ = (const float4*)ldsS;                          \
            float4 a0_ = lp_[h * 4 + 0];                                      \
            float4 a1_ = lp_[h * 4 + 1];                                      \
            float4 a2_ = lp_[h * 4 + 2];                                      \
            float4 a3_ = lp_[h * 4 + 3];                                      \
            float d0_ = fmaf(trx[0], a0_.x, fmaf(trx[1], a0_.y,               \
                        fmaf(trx[2], a0_.z, trx[3] * a0_.w)));                \
            float d1_ = fmaf(trx[4], a1_.x, fmaf(trx[5], a1_.y,               \
                        fmaf(trx[6], a1_.z, trx[7] * a1_.w)));                \
            float d2_ = fmaf(trx[8], a2_.x, fmaf(trx[9], a2_.y,               \
                        fmaf(trx[10], a2_.z, trx[11] * a2_.w)));              \
            float d3_ = fmaf(trx[12], a3_.x, fmaf(trx[13], a3_.y,             \
                        fmaf(trx[14], a3_.z, trx[15] * a3_.w)));              \
            float dh_ = (d0_ + d1_) + (d2_ + d3_);                            \
            Dn_ = SCALED ? dh_ * inv : dh_;                                   \
            D[jn_] = Dn_;                                                     \
        }                                                                     \
        /* partial over l=1..15 (independent of Dn_, schedules in the gap) */ \
        float q0_ = 0.f, q1_ = 0.f, q2_ = 0.f, q3_ = 0.f;                     \
        _Pragma("unroll")                                                     \
        for (int l = 1; l <= 9; l += 4) {                                     \
            q0_ = fmaf(D[(j_ - 1 - l) & 15], ew_[l + 0], q0_);                \
            q1_ = fmaf(D[(j_ - 2 - l) & 15], ew_[l + 1], q1_);                \
            q2_ = fmaf(D[(j_ - 3 - l) & 15], ew_[l + 2], q2_);                \
            q3_ = fmaf(D[(j_ - 4 - l) & 15], ew_[l + 3], q3_);                \
        }                                                                     \
        q0_ = fmaf(D[(j_ - 14) & 15], ew_[13], q0_);                          \
        q1_ = fmaf(D[(j_ - 15) & 15], ew_[14], q1_);                          \
        q2_ = fmaf(D[(j_ - 16) & 15], ew_[15], q2_);                          \
        float p15_ = (q0_ + q1_) + (q2_ + q3_);                               \
        p15_ = (t == 0) ? 0.0f : p15_;     /* O-tag: span len 1 only */       \
        float part_ = fmaf(Dn_, ew_[0], p15_);                                \
        float Sv_ = swap_sum(part_);                                          \
        if (IS_B0) {                                                          \
            float bt_ = etb0 * bem[j_];                                       \
            if (j_ > 0) bt_ = (t == 0) ? 0.0f : bt_;                          \
            Sv_ += bt_;                                                       \
        }                                                                     \
        ldsS[t] = Sv_;                                                        \
        Svk = Sv_;                                                            \
    }

    // ---- first 16-step block ----
    STAGE8(s0)
    if (exact0) {
        SCRF_STEP(0, true, true, false)
#pragma unroll
        for (int j = 1; j < 8; ++j) {
            SCRF_STEP(j, true, false, false)
        }
        STAGE8(s0 + 8)
#pragma unroll
        for (int j = 8; j < 16; ++j) {
            SCRF_STEP(j, true, false, false)
        }
    } else {
#pragma unroll
        for (int j = 0; j < 8; ++j) {
            SCRF_STEP(j, false, false, false)
        }
        STAGE8(s0 + 8)
#pragma unroll
        for (int j = 8; j < 16; ++j) {
            SCRF_STEP(j, false, false, false)
        }
    }

    // ---- remaining blocks ----
    float m_pre = 0.0f;
    for (int b = 1; b < nb; ++b) {
        s0 += 16;
        if (b == preb) {   // capture m at global step c*K-1 (pre-rescale)
            float sv = Svk;
#pragma unroll
            for (int m = 1; m <= 16; m <<= 1) sv += __shfl_xor(sv, m);
            m_pre = mref + __logf(sv);
        }
        // re-anchor: divide all rows by max_t(Sv_last), recenter to e^-20
        float mx = Svk;
#pragma unroll
        for (int m = 1; m <= 16; m <<= 1)
            mx = fmaxf(mx, __shfl_xor(mx, m));
        inv = 2.0611536e-09f / mx;          // e^-20 / mx
        mref += __logf(mx) + 20.0f;
#pragma unroll
        for (int k = 0; k < 16; ++k) D[k] *= inv;

        STAGE8(s0)
        SCRF_STEP(0, false, false, true)    // pending ldsS value gets *inv
#pragma unroll
        for (int j = 1; j < 8; ++j) {
            SCRF_STEP(j, false, false, false)
        }
        STAGE8(s0 + 8)
#pragma unroll
        for (int j = 8; j < 16; ++j) {
            SCRF_STEP(j, false, false, false)
        }
    }
#undef SCRF_STEP
#undef STAGE8

    // ---- chunk outputs ----
    float se = Svk;
#pragma unroll
    for (int m = 1; m <= 16; m <<= 1) se += __shfl_xor(se, m);
    float m_end = mref + __logf(se);
    float contrib = (preb == 0) ? m_end : (m_end - m_pre);
    if (lane == 0) ws2[c] = contrib;
    if (c == C - 1) {
        float etb1 = __expf(w1 * tbound[TT + t]);
        float sc = Svk * etb1;
#pragma unroll
        for (int m = 1; m <= 16; m <<= 1) sc += __shfl_xor(sc, m);
        if (lane == 0) ws2[C] = __logf(sc) - __logf(se);
    }
}

// ---------------------------------------------------------------------------
// Ordered reduction of the C+1 chunk contributions.
// ---------------------------------------------------------------------------
__global__ void stitch_kernel(const float* __restrict__ ws2,
                              float* __restrict__ out, int n) {
    const int lane = (int)threadIdx.x;
    float v = 0.0f;
    for (int i = lane; i < n; i += 64) v += ws2[i];
#pragma unroll
    for (int m = 1; m <= 32; m <<= 1) v += __shfl_xor(v, m);
    if (lane == 0) out[0] = v;
}

// ---------------------------------------------------------------------------
// Fallback (odd S / tiny ws): proven round-2 kernel, reads feats directly.
// ---------------------------------------------------------------------------
__launch_bounds__(64, 1)
__global__ void semicrf_scan_fb_kernel(const float* __restrict__ src,
                                       const float* __restrict__ trans,
                                       const float* __restrict__ tbound,
                                       const float* __restrict__ w1p,
                                       const float* __restrict__ w2p,
                                       float* __restrict__ out, int S) {
    __shared__ float4 ldsS4[8];
    const int lane = threadIdx.x;
    const int t = lane & 31;
    const int h = lane >> 5;
    const float w1 = w1p[0];
    const float w2 = w2p[0];
    const unsigned toff = (unsigned)t * 4u;
    const unsigned planeB = (unsigned)S * 128u;
    const size_t planeE = (size_t)S * TT;

    float trx[16];
#pragma unroll
    for (int i = 0; i < 16; ++i)
        trx[i] = __expf(w1 * trans[t * TT + h * 16 + i]);

    float D[16];
#pragma unroll
    for (int k = 0; k < 16; ++k) D[k] = 0.0f;

    unsigned off[16];
#pragma unroll
    for (int k = 0; k < 16; ++k) {
        int l = (-1 - k) & 15;
        int c = 0 - l; if (c < 0) c = 0;
        off[k] = (unsigned)(l * S + c) * 128u + toff;
    }

    float ring[4][16];
#pragma unroll
    for (int st = 0; st < 4; ++st) {
#pragma unroll
        for (int k = 0; k < 16; ++k)
            ring[st][k] = *(const float*)((const char*)src + off[k]);
        const int qr = st & 15;
        unsigned c = (unsigned)((st + 1 <= S - 1) ? st + 1 : S - 1);
#pragma unroll
        for (int k = 0; k < 16; ++k)
            off[k] = (k == qr) ? (c * 128u + toff) : (off[k] + planeB);
    }

    float etb0 = __expf(w1 * tbound[t]);
    float bem[16];
#pragma unroll
    for (int j = 0; j < 16; ++j)
        bem[j] = __expf(w2 * src[(size_t)j * planeE + (size_t)t]);

    float mref = 0.0f;
    float Svk = 1.0f;

#define FB_STEP(J, S0V, IS_B0)                                                \
    {                                                                         \
        const int j_ = (J);                                                   \
        float ewv[16];                                                        \
        _Pragma("unroll")                                                     \
        for (int k = 0; k < 16; ++k)                                          \
            ewv[k] = __expf(w2 * ring[j_ & 3][k]);                            \
        float p0 = 0.f, p1 = 0.f, p2 = 0.f, p3 = 0.f;                         \
        _Pragma("unroll")                                                     \
        for (int k = 0; k < 16; k += 4) {                                     \
            p0 = fmaf(D[k + 0], ewv[k + 0], p0);                              \
            p1 = fmaf(D[k + 1], ewv[k + 1], p1);                              \
            p2 = fmaf(D[k + 2], ewv[k + 2], p2);                              \
            p3 = fmaf(D[k + 3], ewv[k + 3], p3);                              \
        }                                                                     \
        float part = (p0 + p1) + (p2 + p3);                                   \
        {                                                                     \
            const int kp = (j_ - 1) & 15;                                     \
            float alt = D[kp] * ewv[kp];                                      \
            part = (t == 0) ? alt : part;                                     \
        }                                                                     \
        _Pragma("unroll")                                                     \
        for (int k = 0; k < 16; ++k)                                          \
            ring[(j_ + 4) & 3][k] =                                           \
                *(const float*)((const char*)src + off[k]);                   \
        {                                                                     \
            const int qr = (j_ + 4) & 15;                                     \
            long T1 = (long)(S0V) + j_ + 4 + 1;                               \
            unsigned c_ = (unsigned)(T1 <= (long)(S - 1) ? T1 : (long)(S - 1)); \
            _Pragma("unroll")                                                 \
            for (int k = 0; k < 16; ++k)                                      \
                off[k] = (k == qr) ? (c_ * 128u + toff) : (off[k] + planeB);  \
        }                                                                     \
        float Sv = part + __shfl_xor(part, 32);                               \
        if (IS_B0) {                                                          \
            float bt = etb0 * bem[j_];                                        \
            if (j_ > 0) bt = (t == 0) ? 0.0f : bt;                            \
            Sv += bt;                                                         \
        }                                                                     \
        ((float*)ldsS4)[t] = Sv;                                              \
        __syncthreads();                                                      \
        float4 a0 = ldsS4[h * 4 + 0];                                         \
        float4 a1 = ldsS4[h * 4 + 1];                                         \
        float4 a2 = ldsS4[h * 4 + 2];                                         \
        float4 a3 = ldsS4[h * 4 + 3];                                         \
        float dn0 = fmaf(trx[0],  a0.x, fmaf(trx[1],  a0.y,                   \
                    fmaf(trx[2],  a0.z, trx[3]  * a0.w)));                    \
        float dn1 = fmaf(trx[4],  a1.x, fmaf(trx[5],  a1.y,                   \
                    fmaf(trx[6],  a1.z, trx[7]  * a1.w)));                    \
        float dn2 = fmaf(trx[8],  a2.x, fmaf(trx[9],  a2.y,                   \
                    fmaf(trx[10], a2.z, trx[11] * a2.w)));                    \
        float dn3 = fmaf(trx[12], a3.x, fmaf(trx[13], a3.y,                   \
                    fmaf(trx[14], a3.z, trx[15] * a3.w)));                    \
        D[j_] = (dn0 + dn1) + (dn2 + dn3);                                    \
        Svk = Sv;                                                             \
    }

#pragma unroll
    for (int j = 0; j < 16; ++j) {
        FB_STEP(j, 0L, true)
    }
    const int nblocks = S / 16;
    long s0 = 16;
    for (int b = 1; b < nblocks; ++b) {
        float mx = Svk;
#pragma unroll
        for (int m = 1; m <= 16; m <<= 1)
            mx = fmaxf(mx, __shfl_xor(mx, m));
        float invv = 2.0611536e-09f / mx;
        mref += __logf(mx) + 20.0f;
#pragma unroll
        for (int k = 0; k < 16; ++k) D[k] *= invv;
#pragma unroll
        for (int j = 0; j < 16; ++j) {
            FB_STEP(j, s0, false)
        }
        s0 += 16;
    }
#undef FB_STEP

    float etb1 = __expf(w1 * tbound[TT + t]);
    float val = Svk * etb1;
#pragma unroll
    for (int m = 1; m <= 16; m <<= 1) val += __shfl_xor(val, m);
    if (lane == 0) out[0] = mref + __logf(val);
}

// ---------------------------------------------------------------------------
extern "C" void kernel_launch(void* const* d_in, const int* in_sizes, int n_in,
                              void* d_out, int out_size, void* d_ws, size_t ws_size,
                              hipStream_t stream) {
    const float* feats = (const float*)d_in[0];   // [L=16, S, T=32]
    const float* trans = (const float*)d_in[1];   // [T, T]
    const float* tb    = (const float*)d_in[2];   // [2, T]
    const float* w1    = (const float*)d_in[3];
    const float* w2    = (const float*)d_in[4];
    float* out = (float*)d_out;

    const int n = in_sizes[0];            // L*S*T
    const int S = n / (LL * TT);

    // K=16 chunks; every chunk window is a multiple of 16 steps.
    int C = 0;
    if ((S & 15) == 0 && S >= 64) C = S >> 4;
    const int swz = (C > 0 && (C & 7) == 0) ? 1 : 0;

    const size_t need = (size_t)(C + 2) * sizeof(float);
    if (C > 1 && ws_size >= need) {
        float* ws2 = (float*)d_ws;
        semicrf_chunk_kernel<<<C, 64, 0, stream>>>(feats, trans, tb, w1, w2,
                                                   ws2, S, KCH, C, swz);
        stitch_kernel<<<1, 64, 0, stream>>>(ws2, out, C + 1);
    } else {
        semicrf_scan_fb_kernel<<<1, 64, 0, stream>>>(feats, trans, tb, w1, w2, out, S);
    }
}

// Round 10
// 39.471 us; speedup vs baseline: 1.6467x; 1.4180x over previous
//
#include <hip/hip_runtime.h>

#define TT 32     // tags
#define LL 16     // max span length
#define BURN 32   // burn-in steps for chunk-parallel scan
#define KCH 32    // chunk payload length (steps)

// lane<->lane^32 sum via permlane32_swap (VALU) with shfl fallback
__device__ __forceinline__ float swap_sum(float x) {
#if __has_builtin(__builtin_amdgcn_permlane32_swap)
    typedef unsigned int u2 __attribute__((ext_vector_type(2)));
    u2 r = __builtin_amdgcn_permlane32_swap(__float_as_uint(x), __float_as_uint(x),
                                            false, false);
    return __uint_as_float(r.x) + __uint_as_float(r.y);
#else
    return x + __shfl_xor(x, 32);
#endif
}

// ---------------------------------------------------------------------------
// Chunk-parallel scan; register-staged, double-buffered LDS ring (no LDS-DMA,
// so all waits are counted vmcnt/lgkmcnt and load latency hides under the
// 4-step compute of the previous group).
// Chunk c covers payload steps [cK,(c+1)K); gstart = max(0,cK-BURN); chunks
// with gstart>0 burn in from an all-ones state (projective contraction;
// absmax ~0 verified at BURN=32). Groups of 4 steps: ring parity alternates
// ring0/ring1. Invariant at group g's compute: ring[g&1] holds g's data,
// staged regs hold g+1's data (issued one group earlier). After compute:
// ds_write regs -> ring[(g+1)&1], then issue loads for group g+2.
// Each chunk reports m_end - m_pre of m(x)=log(sum_t H[t]); chunk 0 absolute;
// last chunk adds the terminal correction; ws2 telescopes.
// ---------------------------------------------------------------------------
__launch_bounds__(64, 2)
__global__ void semicrf_chunk_kernel(const float* __restrict__ feats,
                                     const float* __restrict__ trans,
                                     const float* __restrict__ tbound,
                                     const float* __restrict__ w1p,
                                     const float* __restrict__ w2p,
                                     float* __restrict__ ws2,
                                     int S, int K, int C, int swz) {
    __shared__ __align__(16) float ring0[16 * 128];  // 16 planes x 4 steps x 32 t
    __shared__ __align__(16) float ring1[16 * 128];
    __shared__ float ldsS[TT];
    int c = (int)blockIdx.x;
    if (swz) c = (c & 7) * (C >> 3) + (c >> 3);      // XCD-contiguous chunks
    const int lane = (int)threadIdx.x;
    const int t = lane & 31;
    const int h = lane >> 5;
    const float w1 = w1p[0];
    const float w2 = w2p[0];
    const int Sm1 = S - 1;
    const int lane2 = lane * 2;

    int gstart = c * K - BURN;
    if (gstart < 0) gstart = 0;
    const bool exact0 = (gstart == 0);
    const int nb = ((c + 1) * K - gstart) >> 4;   // 16-step blocks in this chunk
    const int preb = (c * K - gstart) >> 4;       // block whose head captures m_pre

    float trx[16];
#pragma unroll
    for (int i = 0; i < 16; ++i)
        trx[i] = __expf(w1 * trans[t * TT + h * 16 + i]);
    float trxsum = 0.0f;
#pragma unroll
    for (int i = 0; i < 16; ++i) trxsum += trx[i];

    float D[16];
#pragma unroll
    for (int k = 0; k < 16; ++k) D[k] = exact0 ? 0.0f : trxsum;
    if (!exact0) ldsS[t] = 1.0f;            // ones init (H_{-1} = 1)

    float etb0 = __expf(w1 * tbound[t]);
    float bem[16];
#pragma unroll
    for (int j = 0; j < 16; ++j) bem[j] = 0.0f;
    if (exact0) {
#pragma unroll
        for (int j = 0; j < 16; ++j)        // bemit[j] = feats[j][0][t]
            bem[j] = __expf(w2 * feats[(size_t)j * (size_t)S * 32u + (size_t)t]);
    }

    float mref = 0.0f, Svk = 1.0f, inv = 1.0f;
    int s0 = gstart;

    float2 gst[16];                          // staged regs: next group's data

// issue 16 coalesced float2 loads for the 4-step group starting at GS
#define LOADG(GS)                                                             \
    {                                                                         \
        int gs_ = (GS); if (gs_ > S - 4) gs_ = S - 4;                         \
        _Pragma("unroll")                                                     \
        for (int l = 0; l < 16; ++l)                                          \
            gst[l] = *(const float2*)(feats +                                 \
                        ((size_t)l * (size_t)Sm1 + (size_t)gs_) * 32 + lane2);\
    }

// write staged regs into ring buffer P (0/1), then issue loads for GSNEXT
#define GROUPOPS(P, GSNEXT)                                                   \
    {                                                                         \
        float* rw_ = (P) ? ring1 : ring0;                                     \
        _Pragma("unroll")                                                     \
        for (int l = 0; l < 16; ++l)                                          \
            *(float2*)&rw_[l * 128 + lane2] = gst[l];                         \
        LOADG(GSNEXT)                                                         \
    }

#define SCRF_STEP(J, IS_B0, IS_FIRST, SCALED)                                 \
    {                                                                         \
        const int j_ = (J);                                                   \
        const int jn_ = (j_ - 1) & 15;                                        \
        const float* rb_ = ((j_ >> 2) & 1) ? ring1 : ring0;                   \
        /* 16 emissions from the ring (conflict-free, bank = t) */            \
        float ew_[16];                                                        \
        _Pragma("unroll")                                                     \
        for (int l = 0; l < 16; ++l)                                          \
            ew_[l] = __expf(w2 * rb_[l * 128 + (j_ & 3) * 32 + t]);           \
        /* MVM from ldsS (Sv written last step) -> D[jn_]  (chain head) */    \
        float Dn_;                                                            \
        if (IS_FIRST) {                                                       \
            Dn_ = 0.0f;                                                       \
        } else {                                                              \
            const float4* lp_ = (const float4*)ldsS;                          \
            float4 a0_ = lp_[h * 4 + 0];                                      \
            float4 a1_ = lp_[h * 4 + 1];                                      \
            float4 a2_ = lp_[h * 4 + 2];                                      \
            float4 a3_ = lp_[h * 4 + 3];                                      \
            float d0_ = fmaf(trx[0], a0_.x, fmaf(trx[1], a0_.y,               \
                        fmaf(trx[2], a0_.z, trx[3] * a0_.w)));                \
            float d1_ = fmaf(trx[4], a1_.x, fmaf(trx[5], a1_.y,               \
                        fmaf(trx[6], a1_.z, trx[7] * a1_.w)));                \
            float d2_ = fmaf(trx[8], a2_.x, fmaf(trx[9], a2_.y,               \
                        fmaf(trx[10], a2_.z, trx[11] * a2_.w)));              \
            float d3_ = fmaf(trx[12], a3_.x, fmaf(trx[13], a3_.y,             \
                        fmaf(trx[14], a3_.z, trx[15] * a3_.w)));              \
            float dh_ = (d0_ + d1_) + (d2_ + d3_);                            \
            Dn_ = SCALED ? dh_ * inv : dh_;                                   \
            D[jn_] = Dn_;                                                     \
        }                                                                     \
        /* partial over l=1..15 (independent of Dn_, schedules in the gap) */ \
        float q0_ = 0.f, q1_ = 0.f, q2_ = 0.f, q3_ = 0.f;                     \
        _Pragma("unroll")                                                     \
        for (int l = 1; l <= 9; l += 4) {                                     \
            q0_ = fmaf(D[(j_ - 1 - l) & 15], ew_[l + 0], q0_);                \
            q1_ = fmaf(D[(j_ - 2 - l) & 15], ew_[l + 1], q1_);                \
            q2_ = fmaf(D[(j_ - 3 - l) & 15], ew_[l + 2], q2_);                \
            q3_ = fmaf(D[(j_ - 4 - l) & 15], ew_[l + 3], q3_);                \
        }                                                                     \
        q0_ = fmaf(D[(j_ - 14) & 15], ew_[13], q0_);                          \
        q1_ = fmaf(D[(j_ - 15) & 15], ew_[14], q1_);                          \
        q2_ = fmaf(D[(j_ - 16) & 15], ew_[15], q2_);                          \
        float p15_ = (q0_ + q1_) + (q2_ + q3_);                               \
        p15_ = (t == 0) ? 0.0f : p15_;     /* O-tag: span len 1 only */       \
        float part_ = fmaf(Dn_, ew_[0], p15_);                                \
        float Sv_ = swap_sum(part_);                                          \
        if (IS_B0) {                                                          \
            float bt_ = etb0 * bem[j_];                                       \
            if (j_ > 0) bt_ = (t == 0) ? 0.0f : bt_;                          \
            Sv_ += bt_;                                                       \
        }                                                                     \
        ldsS[t] = Sv_;                                                        \
        Svk = Sv_;                                                            \
    }

// one 16-step block = 4 groups; ring parity (j>>2)&1; after each group's
// steps, write next group's staged regs and issue loads 2 groups ahead
#define BLOCK16(B0, FIRST, SCALED)                                            \
    SCRF_STEP(0, B0, FIRST, SCALED)                                           \
    SCRF_STEP(1, B0, false, false)                                            \
    SCRF_STEP(2, B0, false, false)                                            \
    SCRF_STEP(3, B0, false, false)                                            \
    GROUPOPS(1, s0 + 8)                                                       \
    SCRF_STEP(4, B0, false, false)                                            \
    SCRF_STEP(5, B0, false, false)                                            \
    SCRF_STEP(6, B0, false, false)                                            \
    SCRF_STEP(7, B0, false, false)                                            \
    GROUPOPS(0, s0 + 12)                                                      \
    SCRF_STEP(8, B0, false, false)                                            \
    SCRF_STEP(9, B0, false, false)                                            \
    SCRF_STEP(10, B0, false, false)                                           \
    SCRF_STEP(11, B0, false, false)                                           \
    GROUPOPS(1, s0 + 16)                                                      \
    SCRF_STEP(12, B0, false, false)                                           \
    SCRF_STEP(13, B0, false, false)                                           \
    SCRF_STEP(14, B0, false, false)                                           \
    SCRF_STEP(15, B0, false, false)                                           \
    GROUPOPS(0, s0 + 20)

    // ---- prologue: stage group 0 into ring0, start group 1 loads ----
    LOADG(s0)
    {
        float* rw_ = ring0;
#pragma unroll
        for (int l = 0; l < 16; ++l)
            *(float2*)&rw_[l * 128 + lane2] = gst[l];
    }
    LOADG(s0 + 4)

    // ---- first 16-step block ----
    if (exact0) {
        BLOCK16(true, true, false)
    } else {
        BLOCK16(false, false, false)
    }

    // ---- remaining blocks ----
    float m_pre = 0.0f;
    for (int b = 1; b < nb; ++b) {
        s0 += 16;
        if (b == preb) {   // capture m at global step c*K-1 (pre-rescale)
            float sv = Svk;
#pragma unroll
            for (int m = 1; m <= 16; m <<= 1) sv += __shfl_xor(sv, m);
            m_pre = mref + __logf(sv);
        }
        // re-anchor: divide all rows by max_t(Sv_last), recenter to e^-20
        float mx = Svk;
#pragma unroll
        for (int m = 1; m <= 16; m <<= 1)
            mx = fmaxf(mx, __shfl_xor(mx, m));
        inv = 2.0611536e-09f / mx;          // e^-20 / mx
        mref += __logf(mx) + 20.0f;
#pragma unroll
        for (int k = 0; k < 16; ++k) D[k] *= inv;

        BLOCK16(false, false, true)
    }
#undef BLOCK16
#undef SCRF_STEP
#undef GROUPOPS
#undef LOADG

    // ---- chunk outputs ----
    float se = Svk;
#pragma unroll
    for (int m = 1; m <= 16; m <<= 1) se += __shfl_xor(se, m);
    float m_end = mref + __logf(se);
    float contrib = (preb == 0) ? m_end : (m_end - m_pre);
    if (lane == 0) ws2[c] = contrib;
    if (c == C - 1) {
        float etb1 = __expf(w1 * tbound[TT + t]);
        float sc = Svk * etb1;
#pragma unroll
        for (int m = 1; m <= 16; m <<= 1) sc += __shfl_xor(sc, m);
        if (lane == 0) ws2[C] = __logf(sc) - __logf(se);
    }
}

// ---------------------------------------------------------------------------
// Ordered reduction of the C+1 chunk contributions.
// ---------------------------------------------------------------------------
__global__ void stitch_kernel(const float* __restrict__ ws2,
                              float* __restrict__ out, int n) {
    const int lane = (int)threadIdx.x;
    float v = 0.0f;
    for (int i = lane; i < n; i += 64) v += ws2[i];
#pragma unroll
    for (int m = 1; m <= 32; m <<= 1) v += __shfl_xor(v, m);
    if (lane == 0) out[0] = v;
}

// ---------------------------------------------------------------------------
// Fallback (odd S / tiny ws): proven round-2 kernel, reads feats directly.
// ---------------------------------------------------------------------------
__launch_bounds__(64, 1)
__global__ void semicrf_scan_fb_kernel(const float* __restrict__ src,
                                       const float* __restrict__ trans,
                                       const float* __restrict__ tbound,
                                       const float* __restrict__ w1p,
                                       const float* __restrict__ w2p,
                                       float* __restrict__ out, int S) {
    __shared__ float4 ldsS4[8];
    const int lane = threadIdx.x;
    const int t = lane & 31;
    const int h = lane >> 5;
    const float w1 = w1p[0];
    const float w2 = w2p[0];
    const unsigned toff = (unsigned)t * 4u;
    const unsigned planeB = (unsigned)S * 128u;
    const size_t planeE = (size_t)S * TT;

    float trx[16];
#pragma unroll
    for (int i = 0; i < 16; ++i)
        trx[i] = __expf(w1 * trans[t * TT + h * 16 + i]);

    float D[16];
#pragma unroll
    for (int k = 0; k < 16; ++k) D[k] = 0.0f;

    unsigned off[16];
#pragma unroll
    for (int k = 0; k < 16; ++k) {
        int l = (-1 - k) & 15;
        int c = 0 - l; if (c < 0) c = 0;
        off[k] = (unsigned)(l * S + c) * 128u + toff;
    }

    float ring[4][16];
#pragma unroll
    for (int st = 0; st < 4; ++st) {
#pragma unroll
        for (int k = 0; k < 16; ++k)
            ring[st][k] = *(const float*)((const char*)src + off[k]);
        const int qr = st & 15;
        unsigned c = (unsigned)((st + 1 <= S - 1) ? st + 1 : S - 1);
#pragma unroll
        for (int k = 0; k < 16; ++k)
            off[k] = (k == qr) ? (c * 128u + toff) : (off[k] + planeB);
    }

    float etb0 = __expf(w1 * tbound[t]);
    float bem[16];
#pragma unroll
    for (int j = 0; j < 16; ++j)
        bem[j] = __expf(w2 * src[(size_t)j * planeE + (size_t)t]);

    float mref = 0.0f;
    float Svk = 1.0f;

#define FB_STEP(J, S0V, IS_B0)                                                \
    {                                                                         \
        const int j_ = (J);                                                   \
        float ewv[16];                                                        \
        _Pragma("unroll")                                                     \
        for (int k = 0; k < 16; ++k)                                          \
            ewv[k] = __expf(w2 * ring[j_ & 3][k]);                            \
        float p0 = 0.f, p1 = 0.f, p2 = 0.f, p3 = 0.f;                         \
        _Pragma("unroll")                                                     \
        for (int k = 0; k < 16; k += 4) {                                     \
            p0 = fmaf(D[k + 0], ewv[k + 0], p0);                              \
            p1 = fmaf(D[k + 1], ewv[k + 1], p1);                              \
            p2 = fmaf(D[k + 2], ewv[k + 2], p2);                              \
            p3 = fmaf(D[k + 3], ewv[k + 3], p3);                              \
        }                                                                     \
        float part = (p0 + p1) + (p2 + p3);                                   \
        {                                                                     \
            const int kp = (j_ - 1) & 15;                                     \
            float alt = D[kp] * ewv[kp];                                      \
            part = (t == 0) ? alt : part;                                     \
        }                                                                     \
        _Pragma("unroll")                                                     \
        for (int k = 0; k < 16; ++k)                                          \
            ring[(j_ + 4) & 3][k] =                                           \
                *(const float*)((const char*)src + off[k]);                   \
        {                                                                     \
            const int qr = (j_ + 4) & 15;                                     \
            long T1 = (long)(S0V) + j_ + 4 + 1;                               \
            unsigned c_ = (unsigned)(T1 <= (long)(S - 1) ? T1 : (long)(S - 1)); \
            _Pragma("unroll")                                                 \
            for (int k = 0; k < 16; ++k)                                      \
                off[k] = (k == qr) ? (c_ * 128u + toff) : (off[k] + planeB);  \
        }                                                                     \
        float Sv = part + __shfl_xor(part, 32);                               \
        if (IS_B0) {                                                          \
            float bt = etb0 * bem[j_];                                        \
            if (j_ > 0) bt = (t == 0) ? 0.0f : bt;                            \
            Sv += bt;                                                         \
        }                                                                     \
        ((float*)ldsS4)[t] = Sv;                                              \
        __syncthreads();                                                      \
        float4 a0 = ldsS4[h * 4 + 0];                                         \
        float4 a1 = ldsS4[h * 4 + 1];                                         \
        float4 a2 = ldsS4[h * 4 + 2];                                         \
        float4 a3 = ldsS4[h * 4 + 3];                                         \
        float dn0 = fmaf(trx[0],  a0.x, fmaf(trx[1],  a0.y,                   \
                    fmaf(trx[2],  a0.z, trx[3]  * a0.w)));                    \
        float dn1 = fmaf(trx[4],  a1.x, fmaf(trx[5],  a1.y,                   \
                    fmaf(trx[6],  a1.z, trx[7]  * a1.w)));                    \
        float dn2 = fmaf(trx[8],  a2.x, fmaf(trx[9],  a2.y,                   \
                    fmaf(trx[10], a2.z, trx[11] * a2.w)));                    \
        float dn3 = fmaf(trx[12], a3.x, fmaf(trx[13], a3.y,                   \
                    fmaf(trx[14], a3.z, trx[15] * a3.w)));                    \
        D[j_] = (dn0 + dn1) + (dn2 + dn3);                                    \
        Svk = Sv;                                                             \
    }

#pragma unroll
    for (int j = 0; j < 16; ++j) {
        FB_STEP(j, 0L, true)
    }
    const int nblocks = S / 16;
    long s0 = 16;
    for (int b = 1; b < nblocks; ++b) {
        float mx = Svk;
#pragma unroll
        for (int m = 1; m <= 16; m <<= 1)
            mx = fmaxf(mx, __shfl_xor(mx, m));
        float invv = 2.0611536e-09f / mx;
        mref += __logf(mx) + 20.0f;
#pragma unroll
        for (int k = 0; k < 16; ++k) D[k] *= invv;
#pragma unroll
        for (int j = 0; j < 16; ++j) {
            FB_STEP(j, s0, false)
        }
        s0 += 16;
    }
#undef FB_STEP

    float etb1 = __expf(w1 * tbound[TT + t]);
    float val = Svk * etb1;
#pragma unroll
    for (int m = 1; m <= 16; m <<= 1) val += __shfl_xor(val, m);
    if (lane == 0) out[0] = mref + __logf(val);
}

// ---------------------------------------------------------------------------
extern "C" void kernel_launch(void* const* d_in, const int* in_sizes, int n_in,
                              void* d_out, int out_size, void* d_ws, size_t ws_size,
                              hipStream_t stream) {
    const float* feats = (const float*)d_in[0];   // [L=16, S, T=32]
    const float* trans = (const float*)d_in[1];   // [T, T]
    const float* tb    = (const float*)d_in[2];   // [2, T]
    const float* w1    = (const float*)d_in[3];
    const float* w2    = (const float*)d_in[4];
    float* out = (float*)d_out;

    const int n = in_sizes[0];            // L*S*T
    const int S = n / (LL * TT);

    // K=32 chunks; chunk windows are multiples of 16 steps (BURN=32).
    int C = 0;
    if ((S & 31) == 0 && S >= 128) C = S >> 5;
    const int swz = (C > 0 && (C & 7) == 0) ? 1 : 0;

    const size_t need = (size_t)(C + 2) * sizeof(float);
    if (C > 1 && ws_size >= need) {
        float* ws2 = (float*)d_ws;
        semicrf_chunk_kernel<<<C, 64, 0, stream>>>(feats, trans, tb, w1, w2,
                                                   ws2, S, KCH, C, swz);
        stitch_kernel<<<1, 64, 0, stream>>>(ws2, out, C + 1);
    } else {
        semicrf_scan_fb_kernel<<<1, 64, 0, stream>>>(feats, trans, tb, w1, w2, out, S);
    }
}